// Round 1
// baseline (2031.020 us; speedup 1.0000x reference)
//
#include <hip/hip_runtime.h>
#include <cstdint>
#include <cstddef>

#define BDIM 512   // 8 waves
#define BB   16    // batch rows per block
#define T_   512
#define F_   128
#define H_   128
#define B_   1024
#define OUTL 15
#define ASTR 264   // LDS A row stride in bf16 elems (128 x | 128 h | 8 pad)
#define HSTR 136   // LDS h-buffer row stride
#define NBLK 64    // blocks per layer role (B_/BB)

typedef __bf16 bf16_t;
typedef __bf16 bf16x8 __attribute__((ext_vector_type(8)));
typedef float  f32x4  __attribute__((ext_vector_type(4)));

__device__ __forceinline__ float u16tof(unsigned int u) {
    unsigned int v = u << 16;
    return __builtin_bit_cast(float, v);
}

__device__ __forceinline__ float sigm(float x) {
    return __builtin_amdgcn_rcpf(1.0f + __expf(-x));
}
__device__ __forceinline__ float tanh_(float x) {
    // tanh(x) = 1 - 2/(exp(2x)+1); exp->inf, rcp(inf)=0 -> clean saturation
    float e = __expf(2.0f * x);
    return 1.0f - 2.0f * __builtin_amdgcn_rcpf(e + 1.0f);
}

__device__ __forceinline__ f32x4 mfma16(bf16x8 a, bf16x8 b, f32x4 c) {
    return __builtin_amdgcn_mfma_f32_16x16x32_bf16(a, b, c, 0, 0, 0);
}

// ---- dtype-generic loads (FW=1: buffer is fp32; FW=0: buffer is bf16) ----
template <int FW>
__device__ __forceinline__ float ldf(const void* p, int i) {
    return FW ? ((const float*)p)[i] : (float)((const bf16_t*)p)[i];
}
template <int FW>
__device__ __forceinline__ bf16x8 ld8(const void* p, size_t off) {
    if (FW) {
        const float* f = (const float*)p + off;
        f32x4 a = *(const f32x4*)f;
        f32x4 b = *(const f32x4*)(f + 4);
        bf16x8 r;
        r[0] = (bf16_t)a[0]; r[1] = (bf16_t)a[1]; r[2] = (bf16_t)a[2]; r[3] = (bf16_t)a[3];
        r[4] = (bf16_t)b[0]; r[5] = (bf16_t)b[1]; r[6] = (bf16_t)b[2]; r[7] = (bf16_t)b[3];
        return r;
    }
    return *(const bf16x8*)((const bf16_t*)p + off);
}
// load 4 x-elements at element offset `ofs`; returns packed bf16x4 + floats
template <int FX>
__device__ __forceinline__ void load_x4(const void* xin, size_t ofs, uint2& pk, float xr[4]) {
    if (FX) {
        f32x4 v = *(const f32x4*)((const float*)xin + ofs);
        union { bf16_t h[4]; uint2 u; } P;
        P.h[0] = (bf16_t)v[0]; P.h[1] = (bf16_t)v[1];
        P.h[2] = (bf16_t)v[2]; P.h[3] = (bf16_t)v[3];
        pk = P.u;
        xr[0] = v[0]; xr[1] = v[1]; xr[2] = v[2]; xr[3] = v[3];
    } else {
        pk = *(const uint2*)((const bf16_t*)xin + ofs);
        xr[0] = u16tof(pk.x & 0xffffu); xr[1] = u16tof(pk.x >> 16);
        xr[2] = u16tof(pk.y & 0xffffu); xr[3] = u16tof(pk.y >> 16);
    }
}

// ---- dtype detection + progress-flag reset ----
__global__ void detect_kernel(const unsigned short* __restrict__ xu, int* __restrict__ flag,
                              int* __restrict__ prog) {
    int lane = threadIdx.x;  // 64 threads
    prog[lane] = 0;          // reset producer/consumer progress (kernel-boundary visible)
    int cnt = 0;
#pragma unroll
    for (int i = 0; i < 16; ++i) {
        unsigned int u = xu[(lane * 16 + i) * 2];   // even u16 index
        unsigned int e = (u >> 7) & 0xffu;          // bf16 exponent field
        cnt += (e >= 100u && e <= 140u) ? 1 : 0;    // plausible N(0,1) bf16 range
    }
#pragma unroll
    for (int s = 32; s > 0; s >>= 1) cnt += __shfl_down(cnt, s, 64);
    if (lane == 0) *flag = (cnt < 512) ? 1 : 0;     // 1 => fp32 buffers
}

template <int FW>
__device__ __forceinline__ void load_gate_frags(
    const void* __restrict__ Wih, const void* __restrict__ Whh,
    const void* __restrict__ bih, const void* __restrict__ bhh,
    int u, int q, bf16x8 wf[4][8], float bias[4])
{
#pragma unroll
    for (int nt = 0; nt < 4; ++nt) {
        int grow = nt * H_ + u;
        bias[nt] = ldf<FW>(bih, grow) + ldf<FW>(bhh, grow);
#pragma unroll
        for (int kt = 0; kt < 8; ++kt) {
            if (kt < 4)
                wf[nt][kt] = ld8<FW>(Wih, (size_t)grow * F_ + kt * 32 + q * 8);
            else
                wf[nt][kt] = ld8<FW>(Whh, (size_t)grow * H_ + (kt - 4) * 32 + q * 8);
        }
    }
}

// ---- encoder layer body ----
// FW: weight/bias dtype; FX: xin dtype; L0: layer-0 role (producer; writes out0, xmean)
// L0==0: consumer role (layer 1); spins on prog[pb] before reading out0 rows.
template <int FW, int FX, int L0>
__device__ __forceinline__ void enc_body(
    int b0,
    const void* __restrict__ xin, size_t xin_rs,      // batch-row stride (elems of FX type)
    bf16_t* __restrict__ xout, size_t xout_rs,        // batch-row stride (bf16 elems)
    const void* __restrict__ Wih, const void* __restrict__ Whh,
    const void* __restrict__ bih, const void* __restrict__ bhh,
    float* __restrict__ xmean, float* __restrict__ ctx,
    bf16_t* __restrict__ hN, float* __restrict__ cN,
    int* __restrict__ prog, int pb,
    bf16_t (*A)[BB * ASTR])
{
    const int tid  = threadIdx.x;
    const int w    = tid >> 6;
    const int lane = tid & 63;
    const int c    = lane & 15;
    const int q    = lane >> 4;
    const int u    = 16 * w + c;

    bf16x8 wf[4][8];
    float  bias[4];
    load_gate_frags<FW>(Wih, Whh, bih, bhh, u, q, wf, bias);

    const int lr   = tid >> 5;
    const int lcol = (tid & 31) * 4;

    float xs[4]  = {0.f, 0.f, 0.f, 0.f};
    float cs[4]  = {0.f, 0.f, 0.f, 0.f};
    float cst[4] = {0.f, 0.f, 0.f, 0.f};

    if (!L0) {
        // wait until producer has published out0[0]
        if (tid == 0) {
            while (__hip_atomic_load(prog + pb, __ATOMIC_RELAXED, __HIP_MEMORY_SCOPE_AGENT) < 1)
                __builtin_amdgcn_s_sleep(4);
            __builtin_amdgcn_fence(__ATOMIC_ACQUIRE, "agent");
        }
        __syncthreads();
    }

    {   // preload x_0, zero h_0
        uint2 pk; float xr[4];
        load_x4<FX>(xin, (size_t)(b0 + lr) * xin_rs + 0 * F_ + lcol, pk, xr);
        *(uint2*)&A[0][lr * ASTR + lcol] = pk;
        uint2 zz; zz.x = 0u; zz.y = 0u;
        *(uint2*)&A[0][lr * ASTR + F_ + lcol] = zz;
        if (L0) { xs[0] += xr[0]; xs[1] += xr[1]; xs[2] += xr[2]; xs[3] += xr[3]; }
    }
    __syncthreads();

    for (int t = 0; t < T_; ++t) {
        const int cur = t & 1, nxt = cur ^ 1;
        const bool havex = (t + 1 < T_);

        if (!L0 && havex) {
            // wait until producer has published out0[t+1] (steady state: no wait)
            if (tid == 0) {
                while (__hip_atomic_load(prog + pb, __ATOMIC_RELAXED, __HIP_MEMORY_SCOPE_AGENT) < t + 2)
                    __builtin_amdgcn_s_sleep(4);
                __builtin_amdgcn_fence(__ATOMIC_ACQUIRE, "agent");
            }
            __syncthreads();
        }

        uint2 pk; float xr[4];
        if (havex)
            load_x4<FX>(xin, (size_t)(b0 + lr) * xin_rs + (size_t)(t + 1) * F_ + lcol, pk, xr);

        f32x4 acc0 = {bias[0], bias[0], bias[0], bias[0]};
        f32x4 acc1 = {bias[1], bias[1], bias[1], bias[1]};
        f32x4 acc2 = {bias[2], bias[2], bias[2], bias[2]};
        f32x4 acc3 = {bias[3], bias[3], bias[3], bias[3]};

        const bf16_t* Ab = &A[cur][0];
#pragma unroll
        for (int kt = 0; kt < 8; ++kt) {
            bf16x8 a = *(const bf16x8*)(Ab + c * ASTR + kt * 32 + q * 8);
            acc0 = mfma16(a, wf[0][kt], acc0);
            acc1 = mfma16(a, wf[1][kt], acc1);
            acc2 = mfma16(a, wf[2][kt], acc2);
            acc3 = mfma16(a, wf[3][kt], acc3);
        }

#pragma unroll
        for (int j = 0; j < 4; ++j) {
            float i_ = sigm(acc0[j]);
            float f_ = sigm(acc1[j]);
            float g_ = tanh_(acc2[j]);
            float o_ = sigm(acc3[j]);
            float cc = f_ * cst[j] + i_ * g_;
            cst[j] = cc;
            float h_ = o_ * tanh_(cc);
            int r = q * 4 + j;
            A[nxt][r * ASTR + F_ + u] = (bf16_t)h_;
            if (L0) {
                xout[(size_t)(b0 + r) * xout_rs + (size_t)t * F_ + u] = (bf16_t)h_;
            } else {
                cs[j] += h_;
                if (t == T_ - 1) {
                    hN[(size_t)(b0 + r) * H_ + u] = (bf16_t)h_;
                    cN[(size_t)(b0 + r) * H_ + u] = cc;
                }
            }
        }

        // x-prefetch store AFTER gate math: global-load latency hides under
        // MFMA-wait + VALU instead of stalling right after the MFMA issue.
        if (havex) {
            *(uint2*)&A[nxt][lr * ASTR + lcol] = pk;
            if (L0) { xs[0] += xr[0]; xs[1] += xr[1]; xs[2] += xr[2]; xs[3] += xr[3]; }
        }
        __syncthreads();

        if (L0 && tid == 0) {
            // barrier above drained all waves' out0 stores to L2; release
            // (wbl2) makes them agent-visible before the flag update.
            __hip_atomic_store(prog + pb, t + 1, __ATOMIC_RELEASE, __HIP_MEMORY_SCOPE_AGENT);
        }
    }

    const float s = 1.0f / (float)T_;
    if (L0) {
        float* dst = xmean + (size_t)(b0 + lr) * F_ + lcol;
        dst[0] = xs[0] * s; dst[1] = xs[1] * s;
        dst[2] = xs[2] * s; dst[3] = xs[3] * s;
    } else {
#pragma unroll
        for (int j = 0; j < 4; ++j)
            ctx[(size_t)(b0 + q * 4 + j) * H_ + u] = cs[j] * s;
    }
}

// fused encoder: blocks 0..63 run layer 0 (producer), 64..127 run layer 1
// (consumer, one step behind). All 128 blocks co-resident (<= 256-CU capacity)
// so the spin cannot deadlock. Pair (b, b+64) maps to the same XCD under
// round-robin dispatch, keeping the handoff L2-local (perf only).
__global__ __launch_bounds__(BDIM) void enc_fused(
    const int* __restrict__ flag,
    void* __restrict__ x,
    const void* Wih0, const void* Whh0, const void* bih0, const void* bhh0,
    const void* Wih1, const void* Whh1, const void* bih1, const void* bhh1,
    float* __restrict__ xmean, float* __restrict__ ctx,
    bf16_t* __restrict__ hN, float* __restrict__ cN,
    int* __restrict__ prog)
{
    __shared__ bf16_t A[2][BB * ASTR];
    const int isf = *flag;
    const int pb  = blockIdx.x & (NBLK - 1);
    const int b0  = pb * BB;
    if (blockIdx.x < NBLK) {
        // layer 0: reads x, writes out0 in-place over x (row-local, causally safe)
        if (isf) enc_body<1, 1, 1>(b0, x, (size_t)T_ * F_, (bf16_t*)x, 2 * (size_t)T_ * F_,
                                   Wih0, Whh0, bih0, bhh0, xmean, nullptr, nullptr, nullptr,
                                   prog, pb, A);
        else     enc_body<0, 0, 1>(b0, x, (size_t)T_ * F_, (bf16_t*)x, (size_t)T_ * F_,
                                   Wih0, Whh0, bih0, bhh0, xmean, nullptr, nullptr, nullptr,
                                   prog, pb, A);
    } else {
        // layer 1: reads out0 (bf16, in x buffer), accumulates ctx, writes finals
        if (isf) enc_body<1, 0, 0>(b0, x, 2 * (size_t)T_ * F_, nullptr, 0,
                                   Wih1, Whh1, bih1, bhh1, nullptr, ctx, hN, cN,
                                   prog, pb, A);
        else     enc_body<0, 0, 0>(b0, x, (size_t)T_ * F_, nullptr, 0,
                                   Wih1, Whh1, bih1, bhh1, nullptr, ctx, hN, cN,
                                   prog, pb, A);
    }
}

// ---- decoder body ----
template <int FW>
__device__ __forceinline__ void dec_body(
    const void* __restrict__ Wih, const void* __restrict__ Whh,
    const void* __restrict__ bih, const void* __restrict__ bhh,
    const void* __restrict__ inW, const void* __restrict__ inb,
    const void* __restrict__ outW, const void* __restrict__ outb,
    const void* __restrict__ attW, const void* __restrict__ attb,
    const float* __restrict__ xmean, const float* __restrict__ ctx,
    const bf16_t* __restrict__ h0, const float* __restrict__ c0,
    void* __restrict__ dout,
    bf16_t* __restrict__ A, bf16_t* __restrict__ Hb, bf16_t* __restrict__ Hb2)
{
    const int tid  = threadIdx.x;
    const int w    = tid >> 6;
    const int lane = tid & 63;
    const int c    = lane & 15;
    const int q    = lane >> 4;
    const int b0   = blockIdx.x * BB;
    const int u    = 16 * w + c;

    bf16x8 wd[4][8];
    float  biasd[4];
    load_gate_frags<FW>(Wih, Whh, bih, bhh, u, q, wd, biasd);

    bf16x8 wa[4], wo[4];
#pragma unroll
    for (int kt = 0; kt < 4; ++kt) {
        wa[kt] = ld8<FW>(attW, (size_t)u * 256 + kt * 32 + q * 8);
        wo[kt] = ld8<FW>(outW, (size_t)u * H_ + kt * 32 + q * 8);
    }
    const float outb_f = ldf<FW>(outb, u);

    const int lr   = tid >> 5;
    const int lcol = (tid & 31) * 4;

    {   // h_x -> A hidden cols
        uint2 hv = *(const uint2*)(h0 + (size_t)(b0 + lr) * H_ + lcol);
        *(uint2*)&A[lr * ASTR + F_ + lcol] = hv;
    }
    {   // xmean -> Hb (bf16), ctx -> Hb2 (bf16)
        const float* xm = xmean + (size_t)(b0 + lr) * F_ + lcol;
        const float* cx = ctx   + (size_t)(b0 + lr) * H_ + lcol;
#pragma unroll
        for (int k = 0; k < 4; ++k) {
            Hb [lr * HSTR + lcol + k] = (bf16_t)xm[k];
            Hb2[lr * HSTR + lcol + k] = (bf16_t)cx[k];
        }
    }
    float cst[4];
#pragma unroll
    for (int j = 0; j < 4; ++j)
        cst[j] = c0[(size_t)(b0 + q * 4 + j) * H_ + u];

    __syncthreads();

    {   // din = xmean @ inW^T + inb  -> A[:, 0:128]
        float b = ldf<FW>(inb, u);
        f32x4 accd = {b, b, b, b};
#pragma unroll
        for (int kt = 0; kt < 4; ++kt) {
            bf16x8 a  = *(const bf16x8*)(Hb + c * HSTR + kt * 32 + q * 8);
            bf16x8 bw = ld8<FW>(inW, (size_t)u * F_ + kt * 32 + q * 8);
            accd = mfma16(a, bw, accd);
        }
#pragma unroll
        for (int j = 0; j < 4; ++j)
            A[(q * 4 + j) * ASTR + u] = (bf16_t)accd[j];
    }
    f32x4 ctxp;
    {   // ctxproj = ctx @ Wa2^T + attn_b  (step-invariant)
        float b = ldf<FW>(attb, u);
        f32x4 acca = {b, b, b, b};
#pragma unroll
        for (int kt = 0; kt < 4; ++kt) {
            bf16x8 a  = *(const bf16x8*)(Hb2 + c * HSTR + kt * 32 + q * 8);
            bf16x8 bw = ld8<FW>(attW, (size_t)u * 256 + 128 + kt * 32 + q * 8);
            acca = mfma16(a, bw, acca);
        }
        ctxp = acca;
    }
    __syncthreads();

    for (int s = 0; s < OUTL; ++s) {
        f32x4 acc0 = {biasd[0], biasd[0], biasd[0], biasd[0]};
        f32x4 acc1 = {biasd[1], biasd[1], biasd[1], biasd[1]};
        f32x4 acc2 = {biasd[2], biasd[2], biasd[2], biasd[2]};
        f32x4 acc3 = {biasd[3], biasd[3], biasd[3], biasd[3]};
#pragma unroll
        for (int kt = 0; kt < 8; ++kt) {
            bf16x8 a = *(const bf16x8*)(A + c * ASTR + kt * 32 + q * 8);
            acc0 = mfma16(a, wd[0][kt], acc0);
            acc1 = mfma16(a, wd[1][kt], acc1);
            acc2 = mfma16(a, wd[2][kt], acc2);
            acc3 = mfma16(a, wd[3][kt], acc3);
        }
#pragma unroll
        for (int j = 0; j < 4; ++j) {
            float i_ = sigm(acc0[j]);
            float f_ = sigm(acc1[j]);
            float g_ = tanh_(acc2[j]);
            float o_ = sigm(acc3[j]);
            float cc = f_ * cst[j] + i_ * g_;
            cst[j] = cc;
            float h_ = o_ * tanh_(cc);
            Hb[(q * 4 + j) * HSTR + u] = (bf16_t)h_;
        }
        __syncthreads();

        f32x4 acch = ctxp;  // h2 = h + h@Wa1^T + ctxproj
#pragma unroll
        for (int kt = 0; kt < 4; ++kt) {
            bf16x8 a = *(const bf16x8*)(Hb + c * HSTR + kt * 32 + q * 8);
            acch = mfma16(a, wa[kt], acch);
        }
#pragma unroll
        for (int j = 0; j < 4; ++j) {
            int r = q * 4 + j;
            float h2 = acch[j] + (float)Hb[r * HSTR + u];
            Hb2[r * HSTR + u]    = (bf16_t)h2;
            A[r * ASTR + F_ + u] = (bf16_t)h2;   // next-step recurrent h
        }
        __syncthreads();   // Hb2 written above is read cross-wave below

        f32x4 acco = {outb_f, outb_f, outb_f, outb_f};  // out = h2 @ outW^T + outb
#pragma unroll
        for (int kt = 0; kt < 4; ++kt) {
            bf16x8 a = *(const bf16x8*)(Hb2 + c * HSTR + kt * 32 + q * 8);
            acco = mfma16(a, wo[kt], acco);
        }
#pragma unroll
        for (int j = 0; j < 4; ++j) {
            int r = q * 4 + j;
            float ov = acco[j];
            size_t oidx = ((size_t)(b0 + r) * OUTL + s) * F_ + u;
            if (FW) ((float*)dout)[oidx] = ov;
            else    ((bf16_t*)dout)[oidx] = (bf16_t)ov;
            A[r * ASTR + u] = (bf16_t)ov;
        }
        __syncthreads();
    }
}

__global__ __launch_bounds__(BDIM) void dec_kernel(
    const int* __restrict__ flag,
    const void* Wih, const void* Whh, const void* bih, const void* bhh,
    const void* inW, const void* inb, const void* outW, const void* outb,
    const void* attW, const void* attb,
    const float* xmean, const float* ctx,
    const bf16_t* h0, const float* c0, void* dout)
{
    __shared__ bf16_t A[BB * ASTR];
    __shared__ bf16_t Hb[BB * HSTR];
    __shared__ bf16_t Hb2[BB * HSTR];
    const int isf = *flag;
    if (isf) dec_body<1>(Wih, Whh, bih, bhh, inW, inb, outW, outb, attW, attb,
                         xmean, ctx, h0, c0, dout, A, Hb, Hb2);
    else     dec_body<0>(Wih, Whh, bih, bhh, inW, inb, outW, outb, attW, attb,
                         xmean, ctx, h0, c0, dout, A, Hb, Hb2);
}

extern "C" void kernel_launch(void* const* d_in, const int* in_sizes, int n_in,
                              void* d_out, int out_size, void* d_ws, size_t ws_size,
                              hipStream_t stream) {
    (void)in_sizes; (void)n_in; (void)out_size; (void)ws_size;

    void*       x     = d_in[0];
    const void* Wih0  = d_in[1];
    const void* Whh0  = d_in[2];
    const void* bih0  = d_in[3];
    const void* bhh0  = d_in[4];
    const void* Wih1  = d_in[5];
    const void* Whh1  = d_in[6];
    const void* bih1  = d_in[7];
    const void* bhh1  = d_in[8];
    const void* dWih  = d_in[9];
    const void* dWhh  = d_in[10];
    const void* dbih  = d_in[11];
    const void* dbhh  = d_in[12];
    const void* inW   = d_in[13];
    const void* inb   = d_in[14];
    const void* outW  = d_in[15];
    const void* outb  = d_in[16];
    const void* attW  = d_in[17];
    const void* attb  = d_in[18];

    int*    flag  = (int*)d_ws;
    int*    prog  = (int*)((char*)d_ws + 16);            // 64 ints
    float*  xmean = (float*)((char*)d_ws + 16 + 256);
    float*  ctx   = xmean + B_ * H_;
    float*  cN    = ctx + B_ * H_;
    bf16_t* hN    = (bf16_t*)(cN + B_ * H_);

    detect_kernel<<<1, 64, 0, stream>>>((const unsigned short*)x, flag, prog);

    // fused encoder: layer-0 producer blocks + layer-1 consumer blocks, 1-step skew
    enc_fused<<<2 * NBLK, BDIM, 0, stream>>>(flag, x,
                                             Wih0, Whh0, bih0, bhh0,
                                             Wih1, Whh1, bih1, bhh1,
                                             xmean, ctx, hN, cN, prog);
    // decoder
    dec_kernel<<<NBLK, BDIM, 0, stream>>>(flag, dWih, dWhh, dbih, dbhh,
                                          inW, inb, outW, outb, attW, attb,
                                          xmean, ctx, hN, cN, d_out);
}

// Round 3
// 1039.822 us; speedup vs baseline: 1.9532x; 1.9532x over previous
//
#include <hip/hip_runtime.h>
#include <cstdint>
#include <cstddef>

#define BDIM 512   // 8 waves
#define BB   16    // batch rows per block
#define T_   512
#define F_   128
#define H_   128
#define B_   1024
#define OUTL 15
#define ASTR 264   // LDS A row stride in bf16 elems (128 x | 128 h | 8 pad)
#define HSTR 136   // LDS h-buffer row stride
#define NBLK 64    // blocks per layer role (B_/BB)
#define CHUNK 8    // producer->consumer handoff granularity (steps per fence)

typedef __bf16 bf16_t;
typedef __bf16 bf16x8 __attribute__((ext_vector_type(8)));
typedef float  f32x4  __attribute__((ext_vector_type(4)));

__device__ __forceinline__ float u16tof(unsigned int u) {
    unsigned int v = u << 16;
    return __builtin_bit_cast(float, v);
}

__device__ __forceinline__ float sigm(float x) {
    return __builtin_amdgcn_rcpf(1.0f + __expf(-x));
}
__device__ __forceinline__ float tanh_(float x) {
    // tanh(x) = 1 - 2/(exp(2x)+1); exp->inf, rcp(inf)=0 -> clean saturation
    float e = __expf(2.0f * x);
    return 1.0f - 2.0f * __builtin_amdgcn_rcpf(e + 1.0f);
}

__device__ __forceinline__ f32x4 mfma16(bf16x8 a, bf16x8 b, f32x4 c) {
    return __builtin_amdgcn_mfma_f32_16x16x32_bf16(a, b, c, 0, 0, 0);
}

// ---- dtype-generic loads (FW=1: buffer is fp32; FW=0: buffer is bf16) ----
template <int FW>
__device__ __forceinline__ float ldf(const void* p, int i) {
    return FW ? ((const float*)p)[i] : (float)((const bf16_t*)p)[i];
}
template <int FW>
__device__ __forceinline__ bf16x8 ld8(const void* p, size_t off) {
    if (FW) {
        const float* f = (const float*)p + off;
        f32x4 a = *(const f32x4*)f;
        f32x4 b = *(const f32x4*)(f + 4);
        bf16x8 r;
        r[0] = (bf16_t)a[0]; r[1] = (bf16_t)a[1]; r[2] = (bf16_t)a[2]; r[3] = (bf16_t)a[3];
        r[4] = (bf16_t)b[0]; r[5] = (bf16_t)b[1]; r[6] = (bf16_t)b[2]; r[7] = (bf16_t)b[3];
        return r;
    }
    return *(const bf16x8*)((const bf16_t*)p + off);
}
// load 4 x-elements at element offset `ofs`; returns packed bf16x4 + floats
template <int FX>
__device__ __forceinline__ void load_x4(const void* xin, size_t ofs, uint2& pk, float xr[4]) {
    if (FX) {
        f32x4 v = *(const f32x4*)((const float*)xin + ofs);
        union { bf16_t h[4]; uint2 u; } P;
        P.h[0] = (bf16_t)v[0]; P.h[1] = (bf16_t)v[1];
        P.h[2] = (bf16_t)v[2]; P.h[3] = (bf16_t)v[3];
        pk = P.u;
        xr[0] = v[0]; xr[1] = v[1]; xr[2] = v[2]; xr[3] = v[3];
    } else {
        pk = *(const uint2*)((const bf16_t*)xin + ofs);
        xr[0] = u16tof(pk.x & 0xffffu); xr[1] = u16tof(pk.x >> 16);
        xr[2] = u16tof(pk.y & 0xffffu); xr[3] = u16tof(pk.y >> 16);
    }
}

// ---- dtype detection + progress-flag reset ----
__global__ void detect_kernel(const unsigned short* __restrict__ xu, int* __restrict__ flag,
                              int* __restrict__ prog) {
    int lane = threadIdx.x;  // 64 threads
    prog[lane] = 0;          // reset producer/consumer progress (kernel-boundary visible)
    int cnt = 0;
#pragma unroll
    for (int i = 0; i < 16; ++i) {
        unsigned int u = xu[(lane * 16 + i) * 2];   // even u16 index
        unsigned int e = (u >> 7) & 0xffu;          // bf16 exponent field
        cnt += (e >= 100u && e <= 140u) ? 1 : 0;    // plausible N(0,1) bf16 range
    }
#pragma unroll
    for (int s = 32; s > 0; s >>= 1) cnt += __shfl_down(cnt, s, 64);
    if (lane == 0) *flag = (cnt < 512) ? 1 : 0;     // 1 => fp32 buffers
}

template <int FW>
__device__ __forceinline__ void load_gate_frags(
    const void* __restrict__ Wih, const void* __restrict__ Whh,
    const void* __restrict__ bih, const void* __restrict__ bhh,
    int u, int q, bf16x8 wf[4][8], float bias[4])
{
#pragma unroll
    for (int nt = 0; nt < 4; ++nt) {
        int grow = nt * H_ + u;
        bias[nt] = ldf<FW>(bih, grow) + ldf<FW>(bhh, grow);
#pragma unroll
        for (int kt = 0; kt < 8; ++kt) {
            if (kt < 4)
                wf[nt][kt] = ld8<FW>(Wih, (size_t)grow * F_ + kt * 32 + q * 8);
            else
                wf[nt][kt] = ld8<FW>(Whh, (size_t)grow * H_ + (kt - 4) * 32 + q * 8);
        }
    }
}

// ---- encoder layer body ----
// FW: weight/bias dtype; FX: xin dtype; L0: layer-0 role (producer; writes out0, xmean)
// L0==0: consumer role (layer 1); chunk-synced on prog[pb] before reading out0 rows.
// Handoff is chunked (CHUNK steps per release/acquire) because agent-scope
// fences on gfx950 are bulk per-XCD L2 writeback/invalidate ops — doing them
// per-step doubled the pipeline rate in round 1.
template <int FW, int FX, int L0>
__device__ __forceinline__ void enc_body(
    int b0,
    const void* __restrict__ xin, size_t xin_rs,      // batch-row stride (elems of FX type)
    bf16_t* __restrict__ xout, size_t xout_rs,        // batch-row stride (bf16 elems)
    const void* __restrict__ Wih, const void* __restrict__ Whh,
    const void* __restrict__ bih, const void* __restrict__ bhh,
    float* __restrict__ xmean, float* __restrict__ ctx,
    bf16_t* __restrict__ hN, float* __restrict__ cN,
    int* __restrict__ prog, int pb,
    bf16_t (*A)[BB * ASTR])
{
    const int tid  = threadIdx.x;
    const int w    = tid >> 6;
    const int lane = tid & 63;
    const int c    = lane & 15;
    const int q    = lane >> 4;
    const int u    = 16 * w + c;

    bf16x8 wf[4][8];
    float  bias[4];
    load_gate_frags<FW>(Wih, Whh, bih, bhh, u, q, wf, bias);

    const int lr   = tid >> 5;
    const int lcol = (tid & 31) * 4;

    float xs[4]  = {0.f, 0.f, 0.f, 0.f};
    float cs[4]  = {0.f, 0.f, 0.f, 0.f};
    float cst[4] = {0.f, 0.f, 0.f, 0.f};

    if (!L0) {
        // wait until producer has published its first chunk (prog >= CHUNK >= 1)
        if (tid == 0) {
            while (__hip_atomic_load(prog + pb, __ATOMIC_RELAXED, __HIP_MEMORY_SCOPE_AGENT) < 1)
                __builtin_amdgcn_s_sleep(2);
            __builtin_amdgcn_fence(__ATOMIC_ACQUIRE, "agent");
        }
        __syncthreads();
    }

    {   // preload x_0, zero h_0
        uint2 pk; float xr[4];
        load_x4<FX>(xin, (size_t)(b0 + lr) * xin_rs + 0 * F_ + lcol, pk, xr);
        *(uint2*)&A[0][lr * ASTR + lcol] = pk;
        uint2 zz; zz.x = 0u; zz.y = 0u;
        *(uint2*)&A[0][lr * ASTR + F_ + lcol] = zz;
        if (L0) { xs[0] += xr[0]; xs[1] += xr[1]; xs[2] += xr[2]; xs[3] += xr[3]; }
    }
    __syncthreads();

    for (int t = 0; t < T_; ++t) {
        const int cur = t & 1, nxt = cur ^ 1;
        const bool havex = (t + 1 < T_);

        // consumer: chunk-boundary sync only (first publish covers t <= CHUNK-2)
        if (!L0 && havex && ((t & (CHUNK - 1)) == (CHUNK - 1))) {
            if (tid == 0) {
                while (__hip_atomic_load(prog + pb, __ATOMIC_RELAXED, __HIP_MEMORY_SCOPE_AGENT) < t + 2)
                    __builtin_amdgcn_s_sleep(2);
                __builtin_amdgcn_fence(__ATOMIC_ACQUIRE, "agent");
            }
            __syncthreads();
        }

        uint2 pk; float xr[4];
        if (havex)
            load_x4<FX>(xin, (size_t)(b0 + lr) * xin_rs + (size_t)(t + 1) * F_ + lcol, pk, xr);

        f32x4 acc0 = {bias[0], bias[0], bias[0], bias[0]};
        f32x4 acc1 = {bias[1], bias[1], bias[1], bias[1]};
        f32x4 acc2 = {bias[2], bias[2], bias[2], bias[2]};
        f32x4 acc3 = {bias[3], bias[3], bias[3], bias[3]};

        const bf16_t* Ab = &A[cur][0];
#pragma unroll
        for (int kt = 0; kt < 8; ++kt) {
            bf16x8 a = *(const bf16x8*)(Ab + c * ASTR + kt * 32 + q * 8);
            acc0 = mfma16(a, wf[0][kt], acc0);
            acc1 = mfma16(a, wf[1][kt], acc1);
            acc2 = mfma16(a, wf[2][kt], acc2);
            acc3 = mfma16(a, wf[3][kt], acc3);
        }

#pragma unroll
        for (int j = 0; j < 4; ++j) {
            float i_ = sigm(acc0[j]);
            float f_ = sigm(acc1[j]);
            float g_ = tanh_(acc2[j]);
            float o_ = sigm(acc3[j]);
            float cc = f_ * cst[j] + i_ * g_;
            cst[j] = cc;
            float h_ = o_ * tanh_(cc);
            int r = q * 4 + j;
            A[nxt][r * ASTR + F_ + u] = (bf16_t)h_;
            if (L0) {
                xout[(size_t)(b0 + r) * xout_rs + (size_t)t * F_ + u] = (bf16_t)h_;
            } else {
                cs[j] += h_;
                if (t == T_ - 1) {
                    hN[(size_t)(b0 + r) * H_ + u] = (bf16_t)h_;
                    cN[(size_t)(b0 + r) * H_ + u] = cc;
                }
            }
        }

        // x-prefetch store AFTER gate math: global-load latency hides under
        // MFMA-wait + VALU instead of stalling right after the MFMA issue.
        if (havex) {
            *(uint2*)&A[nxt][lr * ASTR + lcol] = pk;
            if (L0) { xs[0] += xr[0]; xs[1] += xr[1]; xs[2] += xr[2]; xs[3] += xr[3]; }
        }
        __syncthreads();

        // producer: publish once per chunk; release drains out0 stores to a
        // coherence point once per CHUNK steps instead of every step.
        if (L0 && tid == 0 && (((t + 1) & (CHUNK - 1)) == 0)) {
            __hip_atomic_store(prog + pb, t + 1, __ATOMIC_RELEASE, __HIP_MEMORY_SCOPE_AGENT);
        }
    }

    const float s = 1.0f / (float)T_;
    if (L0) {
        float* dst = xmean + (size_t)(b0 + lr) * F_ + lcol;
        dst[0] = xs[0] * s; dst[1] = xs[1] * s;
        dst[2] = xs[2] * s; dst[3] = xs[3] * s;
    } else {
#pragma unroll
        for (int j = 0; j < 4; ++j)
            ctx[(size_t)(b0 + q * 4 + j) * H_ + u] = cs[j] * s;
    }
}

// fused encoder: blocks 0..63 run layer 0 (producer), 64..127 run layer 1
// (consumer, ~1 chunk behind). All 128 blocks co-resident (<= 256-CU capacity)
// so the spin cannot deadlock. Pair (b, b+64) maps to the same XCD under
// round-robin dispatch, keeping the handoff L2-local (perf only).
__global__ __launch_bounds__(BDIM) void enc_fused(
    const int* __restrict__ flag,
    void* __restrict__ x,
    const void* Wih0, const void* Whh0, const void* bih0, const void* bhh0,
    const void* Wih1, const void* Whh1, const void* bih1, const void* bhh1,
    float* __restrict__ xmean, float* __restrict__ ctx,
    bf16_t* __restrict__ hN, float* __restrict__ cN,
    int* __restrict__ prog)
{
    __shared__ bf16_t A[2][BB * ASTR];
    const int isf = *flag;
    const int pb  = blockIdx.x & (NBLK - 1);
    const int b0  = pb * BB;
    if (blockIdx.x < NBLK) {
        // layer 0: reads x, writes out0 in-place over x (row-local, causally safe)
        if (isf) enc_body<1, 1, 1>(b0, x, (size_t)T_ * F_, (bf16_t*)x, 2 * (size_t)T_ * F_,
                                   Wih0, Whh0, bih0, bhh0, xmean, nullptr, nullptr, nullptr,
                                   prog, pb, A);
        else     enc_body<0, 0, 1>(b0, x, (size_t)T_ * F_, (bf16_t*)x, (size_t)T_ * F_,
                                   Wih0, Whh0, bih0, bhh0, xmean, nullptr, nullptr, nullptr,
                                   prog, pb, A);
    } else {
        // layer 1: reads out0 (bf16, in x buffer), accumulates ctx, writes finals
        if (isf) enc_body<1, 0, 0>(b0, x, 2 * (size_t)T_ * F_, nullptr, 0,
                                   Wih1, Whh1, bih1, bhh1, nullptr, ctx, hN, cN,
                                   prog, pb, A);
        else     enc_body<0, 0, 0>(b0, x, (size_t)T_ * F_, nullptr, 0,
                                   Wih1, Whh1, bih1, bhh1, nullptr, ctx, hN, cN,
                                   prog, pb, A);
    }
}

// ---- decoder body ----
template <int FW>
__device__ __forceinline__ void dec_body(
    const void* __restrict__ Wih, const void* __restrict__ Whh,
    const void* __restrict__ bih, const void* __restrict__ bhh,
    const void* __restrict__ inW, const void* __restrict__ inb,
    const void* __restrict__ outW, const void* __restrict__ outb,
    const void* __restrict__ attW, const void* __restrict__ attb,
    const float* __restrict__ xmean, const float* __restrict__ ctx,
    const bf16_t* __restrict__ h0, const float* __restrict__ c0,
    void* __restrict__ dout,
    bf16_t* __restrict__ A, bf16_t* __restrict__ Hb, bf16_t* __restrict__ Hb2)
{
    const int tid  = threadIdx.x;
    const int w    = tid >> 6;
    const int lane = tid & 63;
    const int c    = lane & 15;
    const int q    = lane >> 4;
    const int b0   = blockIdx.x * BB;
    const int u    = 16 * w + c;

    bf16x8 wd[4][8];
    float  biasd[4];
    load_gate_frags<FW>(Wih, Whh, bih, bhh, u, q, wd, biasd);

    bf16x8 wa[4], wo[4];
#pragma unroll
    for (int kt = 0; kt < 4; ++kt) {
        wa[kt] = ld8<FW>(attW, (size_t)u * 256 + kt * 32 + q * 8);
        wo[kt] = ld8<FW>(outW, (size_t)u * H_ + kt * 32 + q * 8);
    }
    const float outb_f = ldf<FW>(outb, u);

    const int lr   = tid >> 5;
    const int lcol = (tid & 31) * 4;

    {   // h_x -> A hidden cols
        uint2 hv = *(const uint2*)(h0 + (size_t)(b0 + lr) * H_ + lcol);
        *(uint2*)&A[lr * ASTR + F_ + lcol] = hv;
    }
    {   // xmean -> Hb (bf16), ctx -> Hb2 (bf16)
        const float* xm = xmean + (size_t)(b0 + lr) * F_ + lcol;
        const float* cx = ctx   + (size_t)(b0 + lr) * H_ + lcol;
#pragma unroll
        for (int k = 0; k < 4; ++k) {
            Hb [lr * HSTR + lcol + k] = (bf16_t)xm[k];
            Hb2[lr * HSTR + lcol + k] = (bf16_t)cx[k];
        }
    }
    float cst[4];
#pragma unroll
    for (int j = 0; j < 4; ++j)
        cst[j] = c0[(size_t)(b0 + q * 4 + j) * H_ + u];

    __syncthreads();

    {   // din = xmean @ inW^T + inb  -> A[:, 0:128]
        float b = ldf<FW>(inb, u);
        f32x4 accd = {b, b, b, b};
#pragma unroll
        for (int kt = 0; kt < 4; ++kt) {
            bf16x8 a  = *(const bf16x8*)(Hb + c * HSTR + kt * 32 + q * 8);
            bf16x8 bw = ld8<FW>(inW, (size_t)u * F_ + kt * 32 + q * 8);
            accd = mfma16(a, bw, accd);
        }
#pragma unroll
        for (int j = 0; j < 4; ++j)
            A[(q * 4 + j) * ASTR + u] = (bf16_t)accd[j];
    }
    f32x4 ctxp;
    {   // ctxproj = ctx @ Wa2^T + attn_b  (step-invariant)
        float b = ldf<FW>(attb, u);
        f32x4 acca = {b, b, b, b};
#pragma unroll
        for (int kt = 0; kt < 4; ++kt) {
            bf16x8 a  = *(const bf16x8*)(Hb2 + c * HSTR + kt * 32 + q * 8);
            bf16x8 bw = ld8<FW>(attW, (size_t)u * 256 + 128 + kt * 32 + q * 8);
            acca = mfma16(a, bw, acca);
        }
        ctxp = acca;
    }
    __syncthreads();

    for (int s = 0; s < OUTL; ++s) {
        f32x4 acc0 = {biasd[0], biasd[0], biasd[0], biasd[0]};
        f32x4 acc1 = {biasd[1], biasd[1], biasd[1], biasd[1]};
        f32x4 acc2 = {biasd[2], biasd[2], biasd[2], biasd[2]};
        f32x4 acc3 = {biasd[3], biasd[3], biasd[3], biasd[3]};
#pragma unroll
        for (int kt = 0; kt < 8; ++kt) {
            bf16x8 a = *(const bf16x8*)(A + c * ASTR + kt * 32 + q * 8);
            acc0 = mfma16(a, wd[0][kt], acc0);
            acc1 = mfma16(a, wd[1][kt], acc1);
            acc2 = mfma16(a, wd[2][kt], acc2);
            acc3 = mfma16(a, wd[3][kt], acc3);
        }
#pragma unroll
        for (int j = 0; j < 4; ++j) {
            float i_ = sigm(acc0[j]);
            float f_ = sigm(acc1[j]);
            float g_ = tanh_(acc2[j]);
            float o_ = sigm(acc3[j]);
            float cc = f_ * cst[j] + i_ * g_;
            cst[j] = cc;
            float h_ = o_ * tanh_(cc);
            Hb[(q * 4 + j) * HSTR + u] = (bf16_t)h_;
        }
        __syncthreads();

        f32x4 acch = ctxp;  // h2 = h + h@Wa1^T + ctxproj
#pragma unroll
        for (int kt = 0; kt < 4; ++kt) {
            bf16x8 a = *(const bf16x8*)(Hb + c * HSTR + kt * 32 + q * 8);
            acch = mfma16(a, wa[kt], acch);
        }
#pragma unroll
        for (int j = 0; j < 4; ++j) {
            int r = q * 4 + j;
            float h2 = acch[j] + (float)Hb[r * HSTR + u];
            Hb2[r * HSTR + u]    = (bf16_t)h2;
            A[r * ASTR + F_ + u] = (bf16_t)h2;   // next-step recurrent h
        }
        __syncthreads();   // Hb2 written above is read cross-wave below

        f32x4 acco = {outb_f, outb_f, outb_f, outb_f};  // out = h2 @ outW^T + outb
#pragma unroll
        for (int kt = 0; kt < 4; ++kt) {
            bf16x8 a = *(const bf16x8*)(Hb2 + c * HSTR + kt * 32 + q * 8);
            acco = mfma16(a, wo[kt], acco);
        }
#pragma unroll
        for (int j = 0; j < 4; ++j) {
            int r = q * 4 + j;
            float ov = acco[j];
            size_t oidx = ((size_t)(b0 + r) * OUTL + s) * F_ + u;
            if (FW) ((float*)dout)[oidx] = ov;
            else    ((bf16_t*)dout)[oidx] = (bf16_t)ov;
            A[r * ASTR + u] = (bf16_t)ov;
        }
        __syncthreads();
    }
}

__global__ __launch_bounds__(BDIM) void dec_kernel(
    const int* __restrict__ flag,
    const void* Wih, const void* Whh, const void* bih, const void* bhh,
    const void* inW, const void* inb, const void* outW, const void* outb,
    const void* attW, const void* attb,
    const float* xmean, const float* ctx,
    const bf16_t* h0, const float* c0, void* dout)
{
    __shared__ bf16_t A[BB * ASTR];
    __shared__ bf16_t Hb[BB * HSTR];
    __shared__ bf16_t Hb2[BB * HSTR];
    const int isf = *flag;
    if (isf) dec_body<1>(Wih, Whh, bih, bhh, inW, inb, outW, outb, attW, attb,
                         xmean, ctx, h0, c0, dout, A, Hb, Hb2);
    else     dec_body<0>(Wih, Whh, bih, bhh, inW, inb, outW, outb, attW, attb,
                         xmean, ctx, h0, c0, dout, A, Hb, Hb2);
}

extern "C" void kernel_launch(void* const* d_in, const int* in_sizes, int n_in,
                              void* d_out, int out_size, void* d_ws, size_t ws_size,
                              hipStream_t stream) {
    (void)in_sizes; (void)n_in; (void)out_size; (void)ws_size;

    void*       x     = d_in[0];
    const void* Wih0  = d_in[1];
    const void* Whh0  = d_in[2];
    const void* bih0  = d_in[3];
    const void* bhh0  = d_in[4];
    const void* Wih1  = d_in[5];
    const void* Whh1  = d_in[6];
    const void* bih1  = d_in[7];
    const void* bhh1  = d_in[8];
    const void* dWih  = d_in[9];
    const void* dWhh  = d_in[10];
    const void* dbih  = d_in[11];
    const void* dbhh  = d_in[12];
    const void* inW   = d_in[13];
    const void* inb   = d_in[14];
    const void* outW  = d_in[15];
    const void* outb  = d_in[16];
    const void* attW  = d_in[17];
    const void* attb  = d_in[18];

    int*    flag  = (int*)d_ws;
    int*    prog  = (int*)((char*)d_ws + 16);            // 64 ints
    float*  xmean = (float*)((char*)d_ws + 16 + 256);
    float*  ctx   = xmean + B_ * H_;
    float*  cN    = ctx + B_ * H_;
    bf16_t* hN    = (bf16_t*)(cN + B_ * H_);

    detect_kernel<<<1, 64, 0, stream>>>((const unsigned short*)x, flag, prog);

    // fused encoder: layer-0 producer blocks + layer-1 consumer blocks, chunked skew
    enc_fused<<<2 * NBLK, BDIM, 0, stream>>>(flag, x,
                                             Wih0, Whh0, bih0, bhh0,
                                             Wih1, Whh1, bih1, bhh1,
                                             xmean, ctx, hN, cN, prog);
    // decoder
    dec_kernel<<<NBLK, BDIM, 0, stream>>>(flag, dWih, dWhh, dbih, dbhh,
                                          inW, inb, outW, outb, attW, attb,
                                          xmean, ctx, hN, cN, d_out);
}

// Round 7
// 1019.140 us; speedup vs baseline: 1.9929x; 1.0203x over previous
//
#include <hip/hip_runtime.h>
#include <cstdint>
#include <cstddef>

#define BDIM 512   // 8 waves
#define BB   16    // batch rows per block
#define T_   512
#define F_   128
#define H_   128
#define B_   1024
#define OUTL 15
#define ASTR 264   // LDS A row stride in bf16 elems (128 x | 128 h | 8 pad)
#define HSTR 136   // LDS h-buffer row stride
#define NBLK 64    // blocks per layer role (B_/BB)
#define CHUNK 16   // producer->consumer handoff granularity (steps per fence)

typedef __bf16 bf16_t;
typedef __bf16 bf16x8 __attribute__((ext_vector_type(8)));
typedef float  f32x4  __attribute__((ext_vector_type(4)));

__device__ __forceinline__ float u16tof(unsigned int u) {
    unsigned int v = u << 16;
    return __builtin_bit_cast(float, v);
}

__device__ __forceinline__ float sigm(float x) {
    return __builtin_amdgcn_rcpf(1.0f + __expf(-x));
}
__device__ __forceinline__ float tanh_(float x) {
    // tanh(x) = 1 - 2/(exp(2x)+1); exp->inf, rcp(inf)=0 -> clean saturation
    float e = __expf(2.0f * x);
    return 1.0f - 2.0f * __builtin_amdgcn_rcpf(e + 1.0f);
}

__device__ __forceinline__ f32x4 mfma16(bf16x8 a, bf16x8 b, f32x4 c) {
    return __builtin_amdgcn_mfma_f32_16x16x32_bf16(a, b, c, 0, 0, 0);
}

// ---- dtype-generic loads (FW=1: buffer is fp32; FW=0: buffer is bf16) ----
template <int FW>
__device__ __forceinline__ float ldf(const void* p, int i) {
    return FW ? ((const float*)p)[i] : (float)((const bf16_t*)p)[i];
}
template <int FW>
__device__ __forceinline__ bf16x8 ld8(const void* p, size_t off) {
    if (FW) {
        const float* f = (const float*)p + off;
        f32x4 a = *(const f32x4*)f;
        f32x4 b = *(const f32x4*)(f + 4);
        bf16x8 r;
        r[0] = (bf16_t)a[0]; r[1] = (bf16_t)a[1]; r[2] = (bf16_t)a[2]; r[3] = (bf16_t)a[3];
        r[4] = (bf16_t)b[0]; r[5] = (bf16_t)b[1]; r[6] = (bf16_t)b[2]; r[7] = (bf16_t)b[3];
        return r;
    }
    return *(const bf16x8*)((const bf16_t*)p + off);
}
// load 4 x-elements at element offset `ofs`; returns packed bf16x4 + floats
template <int FX>
__device__ __forceinline__ void load_x4(const void* xin, size_t ofs, uint2& pk, float xr[4]) {
    if (FX) {
        f32x4 v = *(const f32x4*)((const float*)xin + ofs);
        union { bf16_t h[4]; uint2 u; } P;
        P.h[0] = (bf16_t)v[0]; P.h[1] = (bf16_t)v[1];
        P.h[2] = (bf16_t)v[2]; P.h[3] = (bf16_t)v[3];
        pk = P.u;
        xr[0] = v[0]; xr[1] = v[1]; xr[2] = v[2]; xr[3] = v[3];
    } else {
        pk = *(const uint2*)((const bf16_t*)xin + ofs);
        xr[0] = u16tof(pk.x & 0xffffu); xr[1] = u16tof(pk.x >> 16);
        xr[2] = u16tof(pk.y & 0xffffu); xr[3] = u16tof(pk.y >> 16);
    }
}

// ---- dtype detection + progress-flag reset ----
__global__ void detect_kernel(const unsigned short* __restrict__ xu, int* __restrict__ flag,
                              int* __restrict__ prog) {
    int lane = threadIdx.x;  // 64 threads
    prog[lane] = 0;          // reset producer/consumer progress (kernel-boundary visible)
    int cnt = 0;
#pragma unroll
    for (int i = 0; i < 16; ++i) {
        unsigned int u = xu[(lane * 16 + i) * 2];   // even u16 index
        unsigned int e = (u >> 7) & 0xffu;          // bf16 exponent field
        cnt += (e >= 100u && e <= 140u) ? 1 : 0;    // plausible N(0,1) bf16 range
    }
#pragma unroll
    for (int s = 32; s > 0; s >>= 1) cnt += __shfl_down(cnt, s, 64);
    if (lane == 0) *flag = (cnt < 512) ? 1 : 0;     // 1 => fp32 buffers
}

template <int FW>
__device__ __forceinline__ void load_gate_frags(
    const void* __restrict__ Wih, const void* __restrict__ Whh,
    const void* __restrict__ bih, const void* __restrict__ bhh,
    int u, int q, bf16x8 wf[4][8], float bias[4])
{
#pragma unroll
    for (int nt = 0; nt < 4; ++nt) {
        int grow = nt * H_ + u;
        bias[nt] = ldf<FW>(bih, grow) + ldf<FW>(bhh, grow);
#pragma unroll
        for (int kt = 0; kt < 8; ++kt) {
            if (kt < 4)
                wf[nt][kt] = ld8<FW>(Wih, (size_t)grow * F_ + kt * 32 + q * 8);
            else
                wf[nt][kt] = ld8<FW>(Whh, (size_t)grow * H_ + (kt - 4) * 32 + q * 8);
        }
    }
}

// ---- encoder layer body ----
// FW: weight/bias dtype; FX: xin dtype; L0: layer-0 role (producer; writes out0, xmean)
// L0==0: consumer role (layer 1); chunk-synced on prog[pb].
// Pipeline: xg_{t+1} = bias + x_{t+1}@Wih is computed DURING step t (x staged 2
// steps ahead in LDS), so the barrier-to-barrier dependent chain is only
// h_t@Whh (4 kt) + gate math. x-loads are issued ~1 step before their LDS store.
template <int FW, int FX, int L0>
__device__ __forceinline__ void enc_body(
    int b0,
    const void* __restrict__ xin, size_t xin_rs,      // batch-row stride (elems of FX type)
    bf16_t* __restrict__ xout, size_t xout_rs,        // batch-row stride (bf16 elems)
    const void* __restrict__ Wih, const void* __restrict__ Whh,
    const void* __restrict__ bih, const void* __restrict__ bhh,
    float* __restrict__ xmean, float* __restrict__ ctx,
    bf16_t* __restrict__ hN, float* __restrict__ cN,
    int* __restrict__ prog, int pb,
    bf16_t (*A)[BB * ASTR])
{
    const int tid  = threadIdx.x;
    const int w    = tid >> 6;
    const int lane = tid & 63;
    const int c    = lane & 15;
    const int q    = lane >> 4;
    const int u    = 16 * w + c;

    bf16x8 wf[4][8];
    float  bias[4];
    load_gate_frags<FW>(Wih, Whh, bih, bhh, u, q, wf, bias);

    const int lr   = tid >> 5;
    const int lcol = (tid & 31) * 4;

    float xs[4]  = {0.f, 0.f, 0.f, 0.f};
    float cs[4]  = {0.f, 0.f, 0.f, 0.f};
    float cst[4] = {0.f, 0.f, 0.f, 0.f};

    if (!L0) {
        // prologue reads rows 0,1 of out0
        if (tid == 0) {
            while (__hip_atomic_load(prog + pb, __ATOMIC_RELAXED, __HIP_MEMORY_SCOPE_AGENT) < 2)
                __builtin_amdgcn_s_sleep(2);
            __builtin_amdgcn_fence(__ATOMIC_ACQUIRE, "agent");
        }
        __syncthreads();
    }

    // ---- prologue: stage x_0, compute xg_0, stage x_1 + zero h_0 ----
    {
        uint2 pk0; float xr0[4];
        load_x4<FX>(xin, (size_t)(b0 + lr) * xin_rs + 0 * F_ + lcol, pk0, xr0);
        *(uint2*)&A[0][lr * ASTR + lcol] = pk0;
        if (L0) { xs[0] += xr0[0]; xs[1] += xr0[1]; xs[2] += xr0[2]; xs[3] += xr0[3]; }
    }
    __syncthreads();

    f32x4 xg0 = {bias[0], bias[0], bias[0], bias[0]};
    f32x4 xg1 = {bias[1], bias[1], bias[1], bias[1]};
    f32x4 xg2 = {bias[2], bias[2], bias[2], bias[2]};
    f32x4 xg3 = {bias[3], bias[3], bias[3], bias[3]};
    {
        const bf16_t* Ab = &A[0][0];
        uint2 pk1; float xr1[4];
        load_x4<FX>(xin, (size_t)(b0 + lr) * xin_rs + 1 * F_ + lcol, pk1, xr1);
#pragma unroll
        for (int kt = 0; kt < 4; ++kt) {
            bf16x8 ax = *(const bf16x8*)(Ab + c * ASTR + kt * 32 + q * 8);
            xg0 = mfma16(ax, wf[0][kt], xg0);
            xg1 = mfma16(ax, wf[1][kt], xg1);
            xg2 = mfma16(ax, wf[2][kt], xg2);
            xg3 = mfma16(ax, wf[3][kt], xg3);
        }
        __syncthreads();   // all waves done reading A[0].x (x_0)
        *(uint2*)&A[0][lr * ASTR + lcol] = pk1;     // x_1 overwrites x_0 slot
        uint2 zz; zz.x = 0u; zz.y = 0u;
        *(uint2*)&A[0][lr * ASTR + F_ + lcol] = zz; // h_0 = 0
        if (L0) { xs[0] += xr1[0]; xs[1] += xr1[1]; xs[2] += xr1[2]; xs[3] += xr1[3]; }
    }
    __syncthreads();

    for (int t = 0; t < T_; ++t) {
        const int P = t & 1, Q = P ^ 1;

        // consumer: chunk-boundary sync; must cover this chunk's x_{t+2} loads
        if (!L0 && ((t & (CHUNK - 1)) == 0)) {
            int need = t + 2 + CHUNK; if (need > T_) need = T_;
            if (tid == 0) {
                while (__hip_atomic_load(prog + pb, __ATOMIC_RELAXED, __HIP_MEMORY_SCOPE_AGENT) < need)
                    __builtin_amdgcn_s_sleep(2);
                __builtin_amdgcn_fence(__ATOMIC_ACQUIRE, "agent");
            }
            __syncthreads();
        }

        const bool ldx = (t + 2 < T_);
        uint2 pk; float xr[4];
        if (ldx)
            load_x4<FX>(xin, (size_t)(b0 + lr) * xin_rs + (size_t)(t + 2) * F_ + lcol, pk, xr);

        const bf16_t* Ab = &A[P][0];

        // critical chain: gates_t = xg_t + h_t @ Whh (4 dependent MFMAs per gate)
        f32x4 a0 = xg0, a1 = xg1, a2 = xg2, a3 = xg3;
#pragma unroll
        for (int kt = 0; kt < 4; ++kt) {
            bf16x8 ah = *(const bf16x8*)(Ab + c * ASTR + F_ + kt * 32 + q * 8);
            a0 = mfma16(ah, wf[0][4 + kt], a0);
            a1 = mfma16(ah, wf[1][4 + kt], a1);
            a2 = mfma16(ah, wf[2][4 + kt], a2);
            a3 = mfma16(ah, wf[3][4 + kt], a3);
        }

        // independent fill work: xg_{t+1} = bias + x_{t+1} @ Wih
        if (t + 1 < T_) {
            xg0 = f32x4{bias[0], bias[0], bias[0], bias[0]};
            xg1 = f32x4{bias[1], bias[1], bias[1], bias[1]};
            xg2 = f32x4{bias[2], bias[2], bias[2], bias[2]};
            xg3 = f32x4{bias[3], bias[3], bias[3], bias[3]};
#pragma unroll
            for (int kt = 0; kt < 4; ++kt) {
                bf16x8 ax = *(const bf16x8*)(Ab + c * ASTR + kt * 32 + q * 8);
                xg0 = mfma16(ax, wf[0][kt], xg0);
                xg1 = mfma16(ax, wf[1][kt], xg1);
                xg2 = mfma16(ax, wf[2][kt], xg2);
                xg3 = mfma16(ax, wf[3][kt], xg3);
            }
        }

#pragma unroll
        for (int j = 0; j < 4; ++j) {
            float i_ = sigm(a0[j]);
            float f_ = sigm(a1[j]);
            float g_ = tanh_(a2[j]);
            float o_ = sigm(a3[j]);
            float cc = f_ * cst[j] + i_ * g_;
            cst[j] = cc;
            float h_ = o_ * tanh_(cc);
            int r = q * 4 + j;
            A[Q][r * ASTR + F_ + u] = (bf16_t)h_;
            if (L0) {
                xout[(size_t)(b0 + r) * xout_rs + (size_t)t * F_ + u] = (bf16_t)h_;
            } else {
                cs[j] += h_;
                if (t == T_ - 1) {
                    hN[(size_t)(b0 + r) * H_ + u] = (bf16_t)h_;
                    cN[(size_t)(b0 + r) * H_ + u] = cc;
                }
            }
        }

        // x_{t+2} LDS store after gate math: global-load latency fully hidden
        if (ldx) {
            *(uint2*)&A[Q][lr * ASTR + lcol] = pk;
            if (L0) { xs[0] += xr[0]; xs[1] += xr[1]; xs[2] += xr[2]; xs[3] += xr[3]; }
        }
        __syncthreads();

        // producer: publish once per chunk (release = L2 writeback, amortized)
        if (L0 && tid == 0 && (((t + 1) & (CHUNK - 1)) == 0)) {
            __hip_atomic_store(prog + pb, t + 1, __ATOMIC_RELEASE, __HIP_MEMORY_SCOPE_AGENT);
        }
    }

    const float s = 1.0f / (float)T_;
    if (L0) {
        float* dst = xmean + (size_t)(b0 + lr) * F_ + lcol;
        dst[0] = xs[0] * s; dst[1] = xs[1] * s;
        dst[2] = xs[2] * s; dst[3] = xs[3] * s;
    } else {
#pragma unroll
        for (int j = 0; j < 4; ++j)
            ctx[(size_t)(b0 + q * 4 + j) * H_ + u] = cs[j] * s;
    }
}

// fused encoder: blocks 0..63 run layer 0 (producer), 64..127 run layer 1
// (consumer, ~2 chunks behind). All 128 blocks co-resident so the spin cannot
// deadlock. __launch_bounds__(512,2): VGPR cap 256 so the 128-VGPR weight
// fragment set stays register-resident (at 128 VGPRs the compiler sank the 32
// weight loads into the t-loop -> per-step L2 refetch, the round-3 bottleneck).
__global__ __launch_bounds__(BDIM, 2) void enc_fused(
    const int* __restrict__ flag,
    void* __restrict__ x,
    const void* Wih0, const void* Whh0, const void* bih0, const void* bhh0,
    const void* Wih1, const void* Whh1, const void* bih1, const void* bhh1,
    float* __restrict__ xmean, float* __restrict__ ctx,
    bf16_t* __restrict__ hN, float* __restrict__ cN,
    int* __restrict__ prog, bf16_t* __restrict__ o0)
{
    __shared__ bf16_t A[2][BB * ASTR];
    const int isf = *flag;
    const int pb  = blockIdx.x & (NBLK - 1);
    const int b0  = pb * BB;
    const size_t TF = (size_t)T_ * F_;
    if (blockIdx.x < NBLK) {
        // layer 0: reads x; writes out0 to workspace (if provided) else in-place
        bf16_t* xo = o0 ? o0 : (bf16_t*)x;
        size_t  ors = o0 ? TF : (isf ? 2 * TF : TF);
        if (isf) enc_body<1, 1, 1>(b0, x, TF, xo, ors, Wih0, Whh0, bih0, bhh0,
                                   xmean, nullptr, nullptr, nullptr, prog, pb, A);
        else     enc_body<0, 0, 1>(b0, x, TF, xo, ors, Wih0, Whh0, bih0, bhh0,
                                   xmean, nullptr, nullptr, nullptr, prog, pb, A);
    } else {
        // layer 1: reads out0 (always bf16), accumulates ctx, writes finals
        const void* xi = o0 ? (const void*)o0 : (const void*)x;
        size_t irs = o0 ? TF : (isf ? 2 * TF : TF);
        if (isf) enc_body<1, 0, 0>(b0, xi, irs, nullptr, 0, Wih1, Whh1, bih1, bhh1,
                                   nullptr, ctx, hN, cN, prog, pb, A);
        else     enc_body<0, 0, 0>(b0, xi, irs, nullptr, 0, Wih1, Whh1, bih1, bhh1,
                                   nullptr, ctx, hN, cN, prog, pb, A);
    }
}

// ---- decoder body ----
template <int FW>
__device__ __forceinline__ void dec_body(
    const void* __restrict__ Wih, const void* __restrict__ Whh,
    const void* __restrict__ bih, const void* __restrict__ bhh,
    const void* __restrict__ inW, const void* __restrict__ inb,
    const void* __restrict__ outW, const void* __restrict__ outb,
    const void* __restrict__ attW, const void* __restrict__ attb,
    const float* __restrict__ xmean, const float* __restrict__ ctx,
    const bf16_t* __restrict__ h0, const float* __restrict__ c0,
    void* __restrict__ dout,
    bf16_t* __restrict__ A, bf16_t* __restrict__ Hb, bf16_t* __restrict__ Hb2)
{
    const int tid  = threadIdx.x;
    const int w    = tid >> 6;
    const int lane = tid & 63;
    const int c    = lane & 15;
    const int q    = lane >> 4;
    const int b0   = blockIdx.x * BB;
    const int u    = 16 * w + c;

    bf16x8 wd[4][8];
    float  biasd[4];
    load_gate_frags<FW>(Wih, Whh, bih, bhh, u, q, wd, biasd);

    bf16x8 wa[4], wo[4];
#pragma unroll
    for (int kt = 0; kt < 4; ++kt) {
        wa[kt] = ld8<FW>(attW, (size_t)u * 256 + kt * 32 + q * 8);
        wo[kt] = ld8<FW>(outW, (size_t)u * H_ + kt * 32 + q * 8);
    }
    const float outb_f = ldf<FW>(outb, u);

    const int lr   = tid >> 5;
    const int lcol = (tid & 31) * 4;

    {   // h_x -> A hidden cols
        uint2 hv = *(const uint2*)(h0 + (size_t)(b0 + lr) * H_ + lcol);
        *(uint2*)&A[lr * ASTR + F_ + lcol] = hv;
    }
    {   // xmean -> Hb (bf16), ctx -> Hb2 (bf16)
        const float* xm = xmean + (size_t)(b0 + lr) * F_ + lcol;
        const float* cx = ctx   + (size_t)(b0 + lr) * H_ + lcol;
#pragma unroll
        for (int k = 0; k < 4; ++k) {
            Hb [lr * HSTR + lcol + k] = (bf16_t)xm[k];
            Hb2[lr * HSTR + lcol + k] = (bf16_t)cx[k];
        }
    }
    float cst[4];
#pragma unroll
    for (int j = 0; j < 4; ++j)
        cst[j] = c0[(size_t)(b0 + q * 4 + j) * H_ + u];

    __syncthreads();

    {   // din = xmean @ inW^T + inb  -> A[:, 0:128]
        float b = ldf<FW>(inb, u);
        f32x4 accd = {b, b, b, b};
#pragma unroll
        for (int kt = 0; kt < 4; ++kt) {
            bf16x8 a  = *(const bf16x8*)(Hb + c * HSTR + kt * 32 + q * 8);
            bf16x8 bw = ld8<FW>(inW, (size_t)u * F_ + kt * 32 + q * 8);
            accd = mfma16(a, bw, accd);
        }
#pragma unroll
        for (int j = 0; j < 4; ++j)
            A[(q * 4 + j) * ASTR + u] = (bf16_t)accd[j];
    }
    f32x4 ctxp;
    {   // ctxproj = ctx @ Wa2^T + attn_b  (step-invariant)
        float b = ldf<FW>(attb, u);
        f32x4 acca = {b, b, b, b};
#pragma unroll
        for (int kt = 0; kt < 4; ++kt) {
            bf16x8 a  = *(const bf16x8*)(Hb2 + c * HSTR + kt * 32 + q * 8);
            bf16x8 bw = ld8<FW>(attW, (size_t)u * 256 + 128 + kt * 32 + q * 8);
            acca = mfma16(a, bw, acca);
        }
        ctxp = acca;
    }
    __syncthreads();

    for (int s = 0; s < OUTL; ++s) {
        f32x4 acc0 = {biasd[0], biasd[0], biasd[0], biasd[0]};
        f32x4 acc1 = {biasd[1], biasd[1], biasd[1], biasd[1]};
        f32x4 acc2 = {biasd[2], biasd[2], biasd[2], biasd[2]};
        f32x4 acc3 = {biasd[3], biasd[3], biasd[3], biasd[3]};
#pragma unroll
        for (int kt = 0; kt < 8; ++kt) {
            bf16x8 a = *(const bf16x8*)(A + c * ASTR + kt * 32 + q * 8);
            acc0 = mfma16(a, wd[0][kt], acc0);
            acc1 = mfma16(a, wd[1][kt], acc1);
            acc2 = mfma16(a, wd[2][kt], acc2);
            acc3 = mfma16(a, wd[3][kt], acc3);
        }
#pragma unroll
        for (int j = 0; j < 4; ++j) {
            float i_ = sigm(acc0[j]);
            float f_ = sigm(acc1[j]);
            float g_ = tanh_(acc2[j]);
            float o_ = sigm(acc3[j]);
            float cc = f_ * cst[j] + i_ * g_;
            cst[j] = cc;
            float h_ = o_ * tanh_(cc);
            Hb[(q * 4 + j) * HSTR + u] = (bf16_t)h_;
        }
        __syncthreads();

        f32x4 acch = ctxp;  // h2 = h + h@Wa1^T + ctxproj
#pragma unroll
        for (int kt = 0; kt < 4; ++kt) {
            bf16x8 a = *(const bf16x8*)(Hb + c * HSTR + kt * 32 + q * 8);
            acch = mfma16(a, wa[kt], acch);
        }
#pragma unroll
        for (int j = 0; j < 4; ++j) {
            int r = q * 4 + j;
            float h2 = acch[j] + (float)Hb[r * HSTR + u];
            Hb2[r * HSTR + u]    = (bf16_t)h2;
            A[r * ASTR + F_ + u] = (bf16_t)h2;   // next-step recurrent h
        }
        __syncthreads();   // Hb2 written above is read cross-wave below

        f32x4 acco = {outb_f, outb_f, outb_f, outb_f};  // out = h2 @ outW^T + outb
#pragma unroll
        for (int kt = 0; kt < 4; ++kt) {
            bf16x8 a = *(const bf16x8*)(Hb2 + c * HSTR + kt * 32 + q * 8);
            acco = mfma16(a, wo[kt], acco);
        }
#pragma unroll
        for (int j = 0; j < 4; ++j) {
            int r = q * 4 + j;
            float ov = acco[j];
            size_t oidx = ((size_t)(b0 + r) * OUTL + s) * F_ + u;
            if (FW) ((float*)dout)[oidx] = ov;
            else    ((bf16_t*)dout)[oidx] = (bf16_t)ov;
            A[r * ASTR + u] = (bf16_t)ov;
        }
        __syncthreads();
    }
}

__global__ __launch_bounds__(BDIM, 2) void dec_kernel(
    const int* __restrict__ flag,
    const void* Wih, const void* Whh, const void* bih, const void* bhh,
    const void* inW, const void* inb, const void* outW, const void* outb,
    const void* attW, const void* attb,
    const float* xmean, const float* ctx,
    const bf16_t* h0, const float* c0, void* dout)
{
    __shared__ bf16_t A[BB * ASTR];
    __shared__ bf16_t Hb[BB * HSTR];
    __shared__ bf16_t Hb2[BB * HSTR];
    const int isf = *flag;
    if (isf) dec_body<1>(Wih, Whh, bih, bhh, inW, inb, outW, outb, attW, attb,
                         xmean, ctx, h0, c0, dout, A, Hb, Hb2);
    else     dec_body<0>(Wih, Whh, bih, bhh, inW, inb, outW, outb, attW, attb,
                         xmean, ctx, h0, c0, dout, A, Hb, Hb2);
}

extern "C" void kernel_launch(void* const* d_in, const int* in_sizes, int n_in,
                              void* d_out, int out_size, void* d_ws, size_t ws_size,
                              hipStream_t stream) {
    (void)in_sizes; (void)n_in; (void)out_size;

    void*       x     = d_in[0];
    const void* Wih0  = d_in[1];
    const void* Whh0  = d_in[2];
    const void* bih0  = d_in[3];
    const void* bhh0  = d_in[4];
    const void* Wih1  = d_in[5];
    const void* Whh1  = d_in[6];
    const void* bih1  = d_in[7];
    const void* bhh1  = d_in[8];
    const void* dWih  = d_in[9];
    const void* dWhh  = d_in[10];
    const void* dbih  = d_in[11];
    const void* dbhh  = d_in[12];
    const void* inW   = d_in[13];
    const void* inb   = d_in[14];
    const void* outW  = d_in[15];
    const void* outb  = d_in[16];
    const void* attW  = d_in[17];
    const void* attb  = d_in[18];

    int*    flag  = (int*)d_ws;
    int*    prog  = (int*)((char*)d_ws + 16);            // 64 ints
    float*  xmean = (float*)((char*)d_ws + 16 + 256);
    float*  ctx   = xmean + B_ * H_;
    float*  cN    = ctx + B_ * H_;
    bf16_t* hN    = (bf16_t*)(cN + B_ * H_);

    // out0 in workspace (avoids modifying input x) if the workspace is big enough
    const size_t REQ = 16 + 256 + 3 * (size_t)B_ * H_ * 4 + (size_t)B_ * H_ * 2
                     + (size_t)B_ * T_ * H_ * 2;
    bf16_t* o0 = (ws_size >= REQ) ? (hN + (size_t)B_ * H_) : nullptr;

    detect_kernel<<<1, 64, 0, stream>>>((const unsigned short*)x, flag, prog);

    // fused encoder: layer-0 producer blocks + layer-1 consumer blocks, chunked skew
    enc_fused<<<2 * NBLK, BDIM, 0, stream>>>(flag, x,
                                             Wih0, Whh0, bih0, bhh0,
                                             Wih1, Whh1, bih1, bhh1,
                                             xmean, ctx, hN, cN, prog, o0);
    // decoder
    dec_kernel<<<NBLK, BDIM, 0, stream>>>(flag, dWih, dWhh, dbih, dbhh,
                                          inW, inb, outW, outb, attW, attb,
                                          xmean, ctx, hN, cN, d_out);
}

// Round 16
// 1009.607 us; speedup vs baseline: 2.0117x; 1.0094x over previous
//
#include <hip/hip_runtime.h>
#include <cstdint>
#include <cstddef>

#define BDIM 512   // 8 waves
#define BB   16    // batch rows per block
#define T_   512
#define F_   128
#define H_   128
#define B_   1024
#define OUTL 15
#define ASTR 264   // LDS A row stride in bf16 elems (128 x | 128 h | 8 pad)
#define HSTR 136   // LDS h-buffer row stride
#define NBLK 64    // blocks per layer role (B_/BB)
#define CHUNK 16   // producer->consumer handoff granularity (steps per fence)

typedef __bf16 bf16_t;
typedef __bf16 bf16x8 __attribute__((ext_vector_type(8)));
typedef float  f32x4  __attribute__((ext_vector_type(4)));
typedef unsigned int u32x4 __attribute__((ext_vector_type(4)));

__device__ __forceinline__ float u16tof(unsigned int u) {
    unsigned int v = u << 16;
    return __builtin_bit_cast(float, v);
}

__device__ __forceinline__ float sigm(float x) {
    return __builtin_amdgcn_rcpf(1.0f + __expf(-x));
}
__device__ __forceinline__ float tanh_(float x) {
    // tanh(x) = 1 - 2/(exp(2x)+1); exp->inf, rcp(inf)=0 -> clean saturation
    float e = __expf(2.0f * x);
    return 1.0f - 2.0f * __builtin_amdgcn_rcpf(e + 1.0f);
}

__device__ __forceinline__ f32x4 mfma16(bf16x8 a, bf16x8 b, f32x4 c) {
    return __builtin_amdgcn_mfma_f32_16x16x32_bf16(a, b, c, 0, 0, 0);
}

// Pin a weight fragment into VGPRs for the lifetime of the enclosing loop.
// The asm defines the value; LLVM cannot rematerialize an asm result by
// re-issuing the original load, so the 4-VGPR tuple stays allocated instead
// of being re-fetched from L2 every timestep (round-7 bottleneck: 256 KB/CU/step).
__device__ __forceinline__ void pin(bf16x8& v) {
    u32x4 t = __builtin_bit_cast(u32x4, v);
    asm volatile("" : "+v"(t));
    v = __builtin_bit_cast(bf16x8, t);
}
__device__ __forceinline__ void pinf(float& v) {
    asm volatile("" : "+v"(v));
}

// ---- dtype-generic loads (FW=1: buffer is fp32; FW=0: buffer is bf16) ----
template <int FW>
__device__ __forceinline__ float ldf(const void* p, int i) {
    return FW ? ((const float*)p)[i] : (float)((const bf16_t*)p)[i];
}
template <int FW>
__device__ __forceinline__ bf16x8 ld8(const void* p, size_t off) {
    if (FW) {
        const float* f = (const float*)p + off;
        f32x4 a = *(const f32x4*)f;
        f32x4 b = *(const f32x4*)(f + 4);
        bf16x8 r;
        r[0] = (bf16_t)a[0]; r[1] = (bf16_t)a[1]; r[2] = (bf16_t)a[2]; r[3] = (bf16_t)a[3];
        r[4] = (bf16_t)b[0]; r[5] = (bf16_t)b[1]; r[6] = (bf16_t)b[2]; r[7] = (bf16_t)b[3];
        return r;
    }
    return *(const bf16x8*)((const bf16_t*)p + off);
}
// load 4 x-elements at element offset `ofs`; returns packed bf16x4 + floats
template <int FX>
__device__ __forceinline__ void load_x4(const void* xin, size_t ofs, uint2& pk, float xr[4]) {
    if (FX) {
        f32x4 v = *(const f32x4*)((const float*)xin + ofs);
        union { bf16_t h[4]; uint2 u; } P;
        P.h[0] = (bf16_t)v[0]; P.h[1] = (bf16_t)v[1];
        P.h[2] = (bf16_t)v[2]; P.h[3] = (bf16_t)v[3];
        pk = P.u;
        xr[0] = v[0]; xr[1] = v[1]; xr[2] = v[2]; xr[3] = v[3];
    } else {
        pk = *(const uint2*)((const bf16_t*)xin + ofs);
        xr[0] = u16tof(pk.x & 0xffffu); xr[1] = u16tof(pk.x >> 16);
        xr[2] = u16tof(pk.y & 0xffffu); xr[3] = u16tof(pk.y >> 16);
    }
}

// ---- dtype detection + progress-flag reset ----
__global__ void detect_kernel(const unsigned short* __restrict__ xu, int* __restrict__ flag,
                              int* __restrict__ prog) {
    int lane = threadIdx.x;  // 64 threads
    prog[lane] = 0;          // reset producer/consumer progress (kernel-boundary visible)
    int cnt = 0;
#pragma unroll
    for (int i = 0; i < 16; ++i) {
        unsigned int u = xu[(lane * 16 + i) * 2];   // even u16 index
        unsigned int e = (u >> 7) & 0xffu;          // bf16 exponent field
        cnt += (e >= 100u && e <= 140u) ? 1 : 0;    // plausible N(0,1) bf16 range
    }
#pragma unroll
    for (int s = 32; s > 0; s >>= 1) cnt += __shfl_down(cnt, s, 64);
    if (lane == 0) *flag = (cnt < 512) ? 1 : 0;     // 1 => fp32 buffers
}

template <int FW>
__device__ __forceinline__ void load_gate_frags(
    const void* __restrict__ Wih, const void* __restrict__ Whh,
    const void* __restrict__ bih, const void* __restrict__ bhh,
    int u, int q, bf16x8 wf[4][8], float bias[4])
{
#pragma unroll
    for (int nt = 0; nt < 4; ++nt) {
        int grow = nt * H_ + u;
        bias[nt] = ldf<FW>(bih, grow) + ldf<FW>(bhh, grow);
#pragma unroll
        for (int kt = 0; kt < 8; ++kt) {
            if (kt < 4)
                wf[nt][kt] = ld8<FW>(Wih, (size_t)grow * F_ + kt * 32 + q * 8);
            else
                wf[nt][kt] = ld8<FW>(Whh, (size_t)grow * H_ + (kt - 4) * 32 + q * 8);
        }
    }
    // force register residency across the time loop
#pragma unroll
    for (int nt = 0; nt < 4; ++nt) {
        pinf(bias[nt]);
#pragma unroll
        for (int kt = 0; kt < 8; ++kt) pin(wf[nt][kt]);
    }
}

// ---- encoder layer body ----
// FW: weight/bias dtype; FX: xin dtype; L0: layer-0 role (producer; writes out0, xmean)
// L0==0: consumer role (layer 1); chunk-synced on prog[pb].
// Pipeline: xg_{t+1} = bias + x_{t+1}@Wih is computed DURING step t (x staged 2
// steps ahead in LDS), so the barrier-to-barrier dependent chain is only
// h_t@Whh (4 kt) + gate math. x-loads are issued ~1 step before their LDS store.
template <int FW, int FX, int L0>
__device__ __forceinline__ void enc_body(
    int b0,
    const void* __restrict__ xin, size_t xin_rs,      // batch-row stride (elems of FX type)
    bf16_t* __restrict__ xout, size_t xout_rs,        // batch-row stride (bf16 elems)
    const void* __restrict__ Wih, const void* __restrict__ Whh,
    const void* __restrict__ bih, const void* __restrict__ bhh,
    float* __restrict__ xmean, float* __restrict__ ctx,
    bf16_t* __restrict__ hN, float* __restrict__ cN,
    int* __restrict__ prog, int pb,
    bf16_t (*A)[BB * ASTR])
{
    const int tid  = threadIdx.x;
    const int w    = tid >> 6;
    const int lane = tid & 63;
    const int c    = lane & 15;
    const int q    = lane >> 4;
    const int u    = 16 * w + c;

    bf16x8 wf[4][8];
    float  bias[4];
    load_gate_frags<FW>(Wih, Whh, bih, bhh, u, q, wf, bias);

    const int lr   = tid >> 5;
    const int lcol = (tid & 31) * 4;

    float xs[4]  = {0.f, 0.f, 0.f, 0.f};
    float cs[4]  = {0.f, 0.f, 0.f, 0.f};
    float cst[4] = {0.f, 0.f, 0.f, 0.f};

    if (!L0) {
        // prologue reads rows 0,1 of out0
        if (tid == 0) {
            while (__hip_atomic_load(prog + pb, __ATOMIC_RELAXED, __HIP_MEMORY_SCOPE_AGENT) < 2)
                __builtin_amdgcn_s_sleep(2);
            __builtin_amdgcn_fence(__ATOMIC_ACQUIRE, "agent");
        }
        __syncthreads();
    }

    // ---- prologue: stage x_0, compute xg_0, stage x_1 + zero h_0 ----
    {
        uint2 pk0; float xr0[4];
        load_x4<FX>(xin, (size_t)(b0 + lr) * xin_rs + 0 * F_ + lcol, pk0, xr0);
        *(uint2*)&A[0][lr * ASTR + lcol] = pk0;
        if (L0) { xs[0] += xr0[0]; xs[1] += xr0[1]; xs[2] += xr0[2]; xs[3] += xr0[3]; }
    }
    __syncthreads();

    f32x4 xg0 = {bias[0], bias[0], bias[0], bias[0]};
    f32x4 xg1 = {bias[1], bias[1], bias[1], bias[1]};
    f32x4 xg2 = {bias[2], bias[2], bias[2], bias[2]};
    f32x4 xg3 = {bias[3], bias[3], bias[3], bias[3]};
    {
        const bf16_t* Ab = &A[0][0];
        uint2 pk1; float xr1[4];
        load_x4<FX>(xin, (size_t)(b0 + lr) * xin_rs + 1 * F_ + lcol, pk1, xr1);
#pragma unroll
        for (int kt = 0; kt < 4; ++kt) {
            bf16x8 ax = *(const bf16x8*)(Ab + c * ASTR + kt * 32 + q * 8);
            xg0 = mfma16(ax, wf[0][kt], xg0);
            xg1 = mfma16(ax, wf[1][kt], xg1);
            xg2 = mfma16(ax, wf[2][kt], xg2);
            xg3 = mfma16(ax, wf[3][kt], xg3);
        }
        __syncthreads();   // all waves done reading A[0].x (x_0)
        *(uint2*)&A[0][lr * ASTR + lcol] = pk1;     // x_1 overwrites x_0 slot
        uint2 zz; zz.x = 0u; zz.y = 0u;
        *(uint2*)&A[0][lr * ASTR + F_ + lcol] = zz; // h_0 = 0
        if (L0) { xs[0] += xr1[0]; xs[1] += xr1[1]; xs[2] += xr1[2]; xs[3] += xr1[3]; }
    }
    __syncthreads();

    for (int t = 0; t < T_; ++t) {
        const int P = t & 1, Q = P ^ 1;

        // consumer: chunk-boundary sync; must cover this chunk's x_{t+2} loads
        if (!L0 && ((t & (CHUNK - 1)) == 0)) {
            int need = t + 2 + CHUNK; if (need > T_) need = T_;
            if (tid == 0) {
                while (__hip_atomic_load(prog + pb, __ATOMIC_RELAXED, __HIP_MEMORY_SCOPE_AGENT) < need)
                    __builtin_amdgcn_s_sleep(2);
                __builtin_amdgcn_fence(__ATOMIC_ACQUIRE, "agent");
            }
            __syncthreads();
        }

        const bool ldx = (t + 2 < T_);
        uint2 pk; float xr[4];
        if (ldx)
            load_x4<FX>(xin, (size_t)(b0 + lr) * xin_rs + (size_t)(t + 2) * F_ + lcol, pk, xr);

        const bf16_t* Ab = &A[P][0];

        // critical chain: gates_t = xg_t + h_t @ Whh (4 dependent MFMAs per gate)
        f32x4 a0 = xg0, a1 = xg1, a2 = xg2, a3 = xg3;
#pragma unroll
        for (int kt = 0; kt < 4; ++kt) {
            bf16x8 ah = *(const bf16x8*)(Ab + c * ASTR + F_ + kt * 32 + q * 8);
            a0 = mfma16(ah, wf[0][4 + kt], a0);
            a1 = mfma16(ah, wf[1][4 + kt], a1);
            a2 = mfma16(ah, wf[2][4 + kt], a2);
            a3 = mfma16(ah, wf[3][4 + kt], a3);
        }

        // independent fill work: xg_{t+1} = bias + x_{t+1} @ Wih
        if (t + 1 < T_) {
            xg0 = f32x4{bias[0], bias[0], bias[0], bias[0]};
            xg1 = f32x4{bias[1], bias[1], bias[1], bias[1]};
            xg2 = f32x4{bias[2], bias[2], bias[2], bias[2]};
            xg3 = f32x4{bias[3], bias[3], bias[3], bias[3]};
#pragma unroll
            for (int kt = 0; kt < 4; ++kt) {
                bf16x8 ax = *(const bf16x8*)(Ab + c * ASTR + kt * 32 + q * 8);
                xg0 = mfma16(ax, wf[0][kt], xg0);
                xg1 = mfma16(ax, wf[1][kt], xg1);
                xg2 = mfma16(ax, wf[2][kt], xg2);
                xg3 = mfma16(ax, wf[3][kt], xg3);
            }
        }

#pragma unroll
        for (int j = 0; j < 4; ++j) {
            float i_ = sigm(a0[j]);
            float f_ = sigm(a1[j]);
            float g_ = tanh_(a2[j]);
            float o_ = sigm(a3[j]);
            float cc = f_ * cst[j] + i_ * g_;
            cst[j] = cc;
            float h_ = o_ * tanh_(cc);
            int r = q * 4 + j;
            A[Q][r * ASTR + F_ + u] = (bf16_t)h_;
            if (L0) {
                xout[(size_t)(b0 + r) * xout_rs + (size_t)t * F_ + u] = (bf16_t)h_;
            } else {
                cs[j] += h_;
                if (t == T_ - 1) {
                    hN[(size_t)(b0 + r) * H_ + u] = (bf16_t)h_;
                    cN[(size_t)(b0 + r) * H_ + u] = cc;
                }
            }
        }

        // x_{t+2} LDS store after gate math: global-load latency fully hidden
        if (ldx) {
            *(uint2*)&A[Q][lr * ASTR + lcol] = pk;
            if (L0) { xs[0] += xr[0]; xs[1] += xr[1]; xs[2] += xr[2]; xs[3] += xr[3]; }
        }
        __syncthreads();

        // producer: publish once per chunk (release = L2 writeback, amortized)
        if (L0 && tid == 0 && (((t + 1) & (CHUNK - 1)) == 0)) {
            __hip_atomic_store(prog + pb, t + 1, __ATOMIC_RELEASE, __HIP_MEMORY_SCOPE_AGENT);
        }
    }

    const float s = 1.0f / (float)T_;
    if (L0) {
        float* dst = xmean + (size_t)(b0 + lr) * F_ + lcol;
        dst[0] = xs[0] * s; dst[1] = xs[1] * s;
        dst[2] = xs[2] * s; dst[3] = xs[3] * s;
    } else {
#pragma unroll
        for (int j = 0; j < 4; ++j)
            ctx[(size_t)(b0 + q * 4 + j) * H_ + u] = cs[j] * s;
    }
}

// fused encoder: blocks 0..63 run layer 0 (producer), 64..127 run layer 1
// (consumer, ~2 chunks behind). All 128 blocks co-resident so the spin cannot
// deadlock. __launch_bounds__(512,2): VGPR cap 256 (8-wave block = 2 waves/SIMD)
// so the pinned 128-VGPR weight set + accumulators (~210) fits. Grid is
// 1 block/CU anyway, so the occupancy loss is free.
__global__ __launch_bounds__(BDIM, 2) void enc_fused(
    const int* __restrict__ flag,
    void* __restrict__ x,
    const void* Wih0, const void* Whh0, const void* bih0, const void* bhh0,
    const void* Wih1, const void* Whh1, const void* bih1, const void* bhh1,
    float* __restrict__ xmean, float* __restrict__ ctx,
    bf16_t* __restrict__ hN, float* __restrict__ cN,
    int* __restrict__ prog, bf16_t* __restrict__ o0)
{
    __shared__ bf16_t A[2][BB * ASTR];
    const int isf = *flag;
    const int pb  = blockIdx.x & (NBLK - 1);
    const int b0  = pb * BB;
    const size_t TF = (size_t)T_ * F_;
    if (blockIdx.x < NBLK) {
        // layer 0: reads x; writes out0 to workspace (if provided) else in-place
        bf16_t* xo = o0 ? o0 : (bf16_t*)x;
        size_t  ors = o0 ? TF : (isf ? 2 * TF : TF);
        if (isf) enc_body<1, 1, 1>(b0, x, TF, xo, ors, Wih0, Whh0, bih0, bhh0,
                                   xmean, nullptr, nullptr, nullptr, prog, pb, A);
        else     enc_body<0, 0, 1>(b0, x, TF, xo, ors, Wih0, Whh0, bih0, bhh0,
                                   xmean, nullptr, nullptr, nullptr, prog, pb, A);
    } else {
        // layer 1: reads out0 (always bf16), accumulates ctx, writes finals
        const void* xi = o0 ? (const void*)o0 : (const void*)x;
        size_t irs = o0 ? TF : (isf ? 2 * TF : TF);
        if (isf) enc_body<1, 0, 0>(b0, xi, irs, nullptr, 0, Wih1, Whh1, bih1, bhh1,
                                   nullptr, ctx, hN, cN, prog, pb, A);
        else     enc_body<0, 0, 0>(b0, xi, irs, nullptr, 0, Wih1, Whh1, bih1, bhh1,
                                   nullptr, ctx, hN, cN, prog, pb, A);
    }
}

// ---- decoder body ----
template <int FW>
__device__ __forceinline__ void dec_body(
    const void* __restrict__ Wih, const void* __restrict__ Whh,
    const void* __restrict__ bih, const void* __restrict__ bhh,
    const void* __restrict__ inW, const void* __restrict__ inb,
    const void* __restrict__ outW, const void* __restrict__ outb,
    const void* __restrict__ attW, const void* __restrict__ attb,
    const float* __restrict__ xmean, const float* __restrict__ ctx,
    const bf16_t* __restrict__ h0, const float* __restrict__ c0,
    void* __restrict__ dout,
    bf16_t* __restrict__ A, bf16_t* __restrict__ Hb, bf16_t* __restrict__ Hb2)
{
    const int tid  = threadIdx.x;
    const int w    = tid >> 6;
    const int lane = tid & 63;
    const int c    = lane & 15;
    const int q    = lane >> 4;
    const int b0   = blockIdx.x * BB;
    const int u    = 16 * w + c;

    bf16x8 wd[4][8];
    float  biasd[4];
    load_gate_frags<FW>(Wih, Whh, bih, bhh, u, q, wd, biasd);

    bf16x8 wa[4], wo[4];
#pragma unroll
    for (int kt = 0; kt < 4; ++kt) {
        wa[kt] = ld8<FW>(attW, (size_t)u * 256 + kt * 32 + q * 8);
        wo[kt] = ld8<FW>(outW, (size_t)u * H_ + kt * 32 + q * 8);
        pin(wa[kt]); pin(wo[kt]);
    }
    const float outb_f = ldf<FW>(outb, u);

    const int lr   = tid >> 5;
    const int lcol = (tid & 31) * 4;

    {   // h_x -> A hidden cols
        uint2 hv = *(const uint2*)(h0 + (size_t)(b0 + lr) * H_ + lcol);
        *(uint2*)&A[lr * ASTR + F_ + lcol] = hv;
    }
    {   // xmean -> Hb (bf16), ctx -> Hb2 (bf16)
        const float* xm = xmean + (size_t)(b0 + lr) * F_ + lcol;
        const float* cx = ctx   + (size_t)(b0 + lr) * H_ + lcol;
#pragma unroll
        for (int k = 0; k < 4; ++k) {
            Hb [lr * HSTR + lcol + k] = (bf16_t)xm[k];
            Hb2[lr * HSTR + lcol + k] = (bf16_t)cx[k];
        }
    }
    float cst[4];
#pragma unroll
    for (int j = 0; j < 4; ++j)
        cst[j] = c0[(size_t)(b0 + q * 4 + j) * H_ + u];

    __syncthreads();

    {   // din = xmean @ inW^T + inb  -> A[:, 0:128]
        float b = ldf<FW>(inb, u);
        f32x4 accd = {b, b, b, b};
#pragma unroll
        for (int kt = 0; kt < 4; ++kt) {
            bf16x8 a  = *(const bf16x8*)(Hb + c * HSTR + kt * 32 + q * 8);
            bf16x8 bw = ld8<FW>(inW, (size_t)u * F_ + kt * 32 + q * 8);
            accd = mfma16(a, bw, accd);
        }
#pragma unroll
        for (int j = 0; j < 4; ++j)
            A[(q * 4 + j) * ASTR + u] = (bf16_t)accd[j];
    }
    f32x4 ctxp;
    {   // ctxproj = ctx @ Wa2^T + attn_b  (step-invariant)
        float b = ldf<FW>(attb, u);
        f32x4 acca = {b, b, b, b};
#pragma unroll
        for (int kt = 0; kt < 4; ++kt) {
            bf16x8 a  = *(const bf16x8*)(Hb2 + c * HSTR + kt * 32 + q * 8);
            bf16x8 bw = ld8<FW>(attW, (size_t)u * 256 + 128 + kt * 32 + q * 8);
            acca = mfma16(a, bw, acca);
        }
        ctxp = acca;
    }
    __syncthreads();

    for (int s = 0; s < OUTL; ++s) {
        f32x4 acc0 = {biasd[0], biasd[0], biasd[0], biasd[0]};
        f32x4 acc1 = {biasd[1], biasd[1], biasd[1], biasd[1]};
        f32x4 acc2 = {biasd[2], biasd[2], biasd[2], biasd[2]};
        f32x4 acc3 = {biasd[3], biasd[3], biasd[3], biasd[3]};
#pragma unroll
        for (int kt = 0; kt < 8; ++kt) {
            bf16x8 a = *(const bf16x8*)(A + c * ASTR + kt * 32 + q * 8);
            acc0 = mfma16(a, wd[0][kt], acc0);
            acc1 = mfma16(a, wd[1][kt], acc1);
            acc2 = mfma16(a, wd[2][kt], acc2);
            acc3 = mfma16(a, wd[3][kt], acc3);
        }
#pragma unroll
        for (int j = 0; j < 4; ++j) {
            float i_ = sigm(acc0[j]);
            float f_ = sigm(acc1[j]);
            float g_ = tanh_(acc2[j]);
            float o_ = sigm(acc3[j]);
            float cc = f_ * cst[j] + i_ * g_;
            cst[j] = cc;
            float h_ = o_ * tanh_(cc);
            Hb[(q * 4 + j) * HSTR + u] = (bf16_t)h_;
        }
        __syncthreads();

        f32x4 acch = ctxp;  // h2 = h + h@Wa1^T + ctxproj
#pragma unroll
        for (int kt = 0; kt < 4; ++kt) {
            bf16x8 a = *(const bf16x8*)(Hb + c * HSTR + kt * 32 + q * 8);
            acch = mfma16(a, wa[kt], acch);
        }
#pragma unroll
        for (int j = 0; j < 4; ++j) {
            int r = q * 4 + j;
            float h2 = acch[j] + (float)Hb[r * HSTR + u];
            Hb2[r * HSTR + u]    = (bf16_t)h2;
            A[r * ASTR + F_ + u] = (bf16_t)h2;   // next-step recurrent h
        }
        __syncthreads();   // Hb2 written above is read cross-wave below

        f32x4 acco = {outb_f, outb_f, outb_f, outb_f};  // out = h2 @ outW^T + outb
#pragma unroll
        for (int kt = 0; kt < 4; ++kt) {
            bf16x8 a = *(const bf16x8*)(Hb2 + c * HSTR + kt * 32 + q * 8);
            acco = mfma16(a, wo[kt], acco);
        }
#pragma unroll
        for (int j = 0; j < 4; ++j) {
            int r = q * 4 + j;
            float ov = acco[j];
            size_t oidx = ((size_t)(b0 + r) * OUTL + s) * F_ + u;
            if (FW) ((float*)dout)[oidx] = ov;
            else    ((bf16_t*)dout)[oidx] = (bf16_t)ov;
            A[r * ASTR + u] = (bf16_t)ov;
        }
        __syncthreads();
    }
}

__global__ __launch_bounds__(BDIM, 2) void dec_kernel(
    const int* __restrict__ flag,
    const void* Wih, const void* Whh, const void* bih, const void* bhh,
    const void* inW, const void* inb, const void* outW, const void* outb,
    const void* attW, const void* attb,
    const float* xmean, const float* ctx,
    const bf16_t* h0, const float* c0, void* dout)
{
    __shared__ bf16_t A[BB * ASTR];
    __shared__ bf16_t Hb[BB * HSTR];
    __shared__ bf16_t Hb2[BB * HSTR];
    const int isf = *flag;
    if (isf) dec_body<1>(Wih, Whh, bih, bhh, inW, inb, outW, outb, attW, attb,
                         xmean, ctx, h0, c0, dout, A, Hb, Hb2);
    else     dec_body<0>(Wih, Whh, bih, bhh, inW, inb, outW, outb, attW, attb,
                         xmean, ctx, h0, c0, dout, A, Hb, Hb2);
}

extern "C" void kernel_launch(void* const* d_in, const int* in_sizes, int n_in,
                              void* d_out, int out_size, void* d_ws, size_t ws_size,
                              hipStream_t stream) {
    (void)in_sizes; (void)n_in; (void)out_size;

    void*       x     = d_in[0];
    const void* Wih0  = d_in[1];
    const void* Whh0  = d_in[2];
    const void* bih0  = d_in[3];
    const void* bhh0  = d_in[4];
    const void* Wih1  = d_in[5];
    const void* Whh1  = d_in[6];
    const void* bih1  = d_in[7];
    const void* bhh1  = d_in[8];
    const void* dWih  = d_in[9];
    const void* dWhh  = d_in[10];
    const void* dbih  = d_in[11];
    const void* dbhh  = d_in[12];
    const void* inW   = d_in[13];
    const void* inb   = d_in[14];
    const void* outW  = d_in[15];
    const void* outb  = d_in[16];
    const void* attW  = d_in[17];
    const void* attb  = d_in[18];

    int*    flag  = (int*)d_ws;
    int*    prog  = (int*)((char*)d_ws + 16);            // 64 ints
    float*  xmean = (float*)((char*)d_ws + 16 + 256);
    float*  ctx   = xmean + B_ * H_;
    float*  cN    = ctx + B_ * H_;
    bf16_t* hN    = (bf16_t*)(cN + B_ * H_);

    // out0 in workspace (avoids modifying input x) if the workspace is big enough
    const size_t REQ = 16 + 256 + 3 * (size_t)B_ * H_ * 4 + (size_t)B_ * H_ * 2
                     + (size_t)B_ * T_ * H_ * 2;
    bf16_t* o0 = (ws_size >= REQ) ? (hN + (size_t)B_ * H_) : nullptr;

    detect_kernel<<<1, 64, 0, stream>>>((const unsigned short*)x, flag, prog);

    // fused encoder: layer-0 producer blocks + layer-1 consumer blocks, chunked skew
    enc_fused<<<2 * NBLK, BDIM, 0, stream>>>(flag, x,
                                             Wih0, Whh0, bih0, bhh0,
                                             Wih1, Whh1, bih1, bhh1,
                                             xmean, ctx, hN, cN, prog, o0);
    // decoder
    dec_kernel<<<NBLK, BDIM, 0, stream>>>(flag, dWih, dWhh, dbih, dbhh,
                                          inW, inb, outW, outb, attW, attb,
                                          xmean, ctx, hN, cN, d_out);
}